// Round 1
// baseline (3219.846 us; speedup 1.0000x reference)
//
#include <hip/hip_runtime.h>
#include <math.h>

static constexpr int D = 128;
static constexpr float EPS_BN = 1e-3f;

__device__ __forceinline__ float gelu_exact(float x) {
    return 0.5f * x * (1.0f + erff(x * 0.70710678118654752f));
}

// ---------------- edge-weight sum ----------------
__global__ void k_sum(const float* __restrict__ w, int n, float* __restrict__ out) {
    float s = 0.f;
    for (int i = blockIdx.x * blockDim.x + threadIdx.x; i < n; i += gridDim.x * blockDim.x)
        s += w[i];
    for (int off = 32; off > 0; off >>= 1) s += __shfl_down(s, off, 64);
    __shared__ float sm[4];
    int lane = threadIdx.x & 63, wv = threadIdx.x >> 6;
    if (lane == 0) sm[wv] = s;
    __syncthreads();
    if (threadIdx.x == 0) atomicAdd(out, sm[0] + sm[1] + sm[2] + sm[3]);
}

__global__ void k_recip(float* s) { s[1] = 1.0f / s[0]; }

// ---------------- fold BN into weights: Wt[c][k] = a_k * W[k][c], bp = bi + sum_k c_k W[k][c]
__global__ void k_fold(const float* __restrict__ g, const float* __restrict__ be,
                       const float* __restrict__ mu, const float* __restrict__ var,
                       const float* __restrict__ w, const float* __restrict__ bi,
                       float* __restrict__ wt, float* __restrict__ bp, int K) {
    int c = blockIdx.x; // 0..127
    float part = 0.f;
    for (int k = threadIdx.x; k < K; k += blockDim.x) {
        float a = g[k] / sqrtf(var[k] + EPS_BN);
        float wv = w[k * D + c];
        wt[c * K + k] = a * wv;
        part += (be[k] - mu[k] * a) * wv;
    }
    for (int off = 32; off > 0; off >>= 1) part += __shfl_down(part, off, 64);
    __shared__ float sm[4];
    int lane = threadIdx.x & 63, wv_ = threadIdx.x >> 6;
    if (lane == 0) sm[wv_] = part;
    __syncthreads();
    if (threadIdx.x == 0) bp[c] = bi[c] + sm[0] + sm[1] + sm[2] + sm[3];
}

// ---------------- fused FFN GEMM: out = gelu(A @ W' + b'), optional l2norm+residual
// A: [nrows][K] (K=256 -> concat of A0,A1 halves, each stride 128). W' col-major [128][K].
template<int K, bool L2RES>
__global__ __launch_bounds__(256, 2) void k_ffn(
    const float* __restrict__ A0, const float* __restrict__ A1,
    const float* __restrict__ Wt, const float* __restrict__ bp,
    const float* __restrict__ resid, float* __restrict__ out, int nrows)
{
    constexpr int KC = 64;
    __shared__ float4 Alds[64 * 17];   // [r][k4], stride 17 float4 (68 floats) -> 2-way max
    __shared__ float4 Wlds[128 * 16];  // [c][k4 ^ (c&7)] swizzled, stride 16 float4

    const int tid = threadIdx.x;
    const int lane = tid & 63;
    const int wv = tid >> 6;
    const int lx = lane & 15;   // col group: cols lx + 16*j
    const int ly = lane >> 4;   // row group: rows wv*16 + ly*4 + i
    const int rowBlock = blockIdx.x * 64;
    const int swz = lx & 7;

    float acc[4][8];
    #pragma unroll
    for (int i = 0; i < 4; i++)
        #pragma unroll
        for (int j = 0; j < 8; j++) acc[i][j] = 0.f;

    for (int cc = 0; cc < K / KC; cc++) {
        const int k0 = cc * KC;
        const float* Asrc = (K == 256 && k0 >= 128) ? A1 : A0;
        const int kbase = (K == 256 && k0 >= 128) ? (k0 - 128) : k0;

        #pragma unroll
        for (int t = 0; t < 4; t++) {           // stage A: 64 rows x 16 float4
            int i = tid + t * 256;
            int r = i >> 4, k4 = i & 15;
            int grow = rowBlock + r; if (grow >= nrows) grow = nrows - 1;
            Alds[r * 17 + k4] = *((const float4*)(Asrc + (size_t)grow * D + kbase) + k4);
        }
        #pragma unroll
        for (int t = 0; t < 8; t++) {           // stage W: 128 cols x 16 float4
            int i = tid + t * 256;
            int c = i >> 4, k4 = i & 15;
            Wlds[c * 16 + (k4 ^ (c & 7))] = *((const float4*)Wt + c * (K / 4) + (k0 >> 2) + k4);
        }
        __syncthreads();

        #pragma unroll
        for (int k4 = 0; k4 < 16; k4++) {
            float4 a[4], w[8];
            #pragma unroll
            for (int i = 0; i < 4; i++)
                a[i] = Alds[(wv * 16 + ly * 4 + i) * 17 + k4];
            const int wk = k4 ^ swz;
            #pragma unroll
            for (int j = 0; j < 8; j++)
                w[j] = Wlds[(lx + 16 * j) * 16 + wk];
            #pragma unroll
            for (int i = 0; i < 4; i++)
                #pragma unroll
                for (int j = 0; j < 8; j++) {
                    acc[i][j] += a[i].x * w[j].x;
                    acc[i][j] += a[i].y * w[j].y;
                    acc[i][j] += a[i].z * w[j].z;
                    acc[i][j] += a[i].w * w[j].w;
                }
        }
        __syncthreads();
    }

    float bv[8];
    #pragma unroll
    for (int j = 0; j < 8; j++) bv[j] = bp[lx + 16 * j];

    #pragma unroll
    for (int i = 0; i < 4; i++) {
        int r = rowBlock + wv * 16 + ly * 4 + i;
        float g[8];
        #pragma unroll
        for (int j = 0; j < 8; j++) g[j] = gelu_exact(acc[i][j] + bv[j]);
        if (L2RES) {
            float ss = 0.f;
            #pragma unroll
            for (int j = 0; j < 8; j++) ss += g[j] * g[j];
            ss += __shfl_xor(ss, 1, 64);
            ss += __shfl_xor(ss, 2, 64);
            ss += __shfl_xor(ss, 4, 64);
            ss += __shfl_xor(ss, 8, 64);
            float inv = 1.0f / fmaxf(sqrtf(ss), 1e-12f);
            if (r < nrows) {
                #pragma unroll
                for (int j = 0; j < 8; j++)
                    out[(size_t)r * D + lx + 16 * j] = g[j] * inv + resid[(size_t)r * D + lx + 16 * j];
            }
        } else {
            if (r < nrows) {
                #pragma unroll
                for (int j = 0; j < 8; j++)
                    out[(size_t)r * D + lx + 16 * j] = g[j];
            }
        }
    }
}

// ---------------- edge scatter: red[dst] += y[src] * (ew[e] * inv_sum)
__global__ void k_scatter(const int* __restrict__ edges, const float* __restrict__ ew,
                          const float* __restrict__ sums, const float* __restrict__ y,
                          float* __restrict__ red, int E) {
    long long g = (long long)blockIdx.x * blockDim.x + threadIdx.x;
    int e = (int)(g >> 5);
    int l = (int)(g & 31);
    if (e >= E) return;
    int dst = edges[e];
    int src = edges[E + e];
    float w = ew[e] * sums[1];
    float4 v = *((const float4*)(y + (size_t)src * D) + l);
    float* rp = red + (size_t)dst * D + l * 4;
    atomicAdd(rp + 0, v.x * w);
    atomicAdd(rp + 1, v.y * w);
    atomicAdd(rp + 2, v.z * w);
    atomicAdd(rp + 3, v.w * w);
}

// ---------------- gather + logits: out[b] = x[idx[b]] @ LW + lb   (one wave per row)
__global__ void k_logits(const float* __restrict__ x, const int* __restrict__ idx,
                         const float* __restrict__ LW, const float* __restrict__ lb,
                         float* __restrict__ out, int B) {
    int wid = blockIdx.x * 4 + (threadIdx.x >> 6);
    int lane = threadIdx.x & 63;
    if (wid >= B) return;
    int row = __builtin_amdgcn_readfirstlane(idx[wid]);
    if (lane >= 40) return;
    float acc = lb[lane];
    const float4* xr = (const float4*)(x + (size_t)row * D);
    #pragma unroll 4
    for (int k4 = 0; k4 < 32; k4++) {
        float4 xv = xr[k4];
        acc += xv.x * LW[(4 * k4 + 0) * 40 + lane];
        acc += xv.y * LW[(4 * k4 + 1) * 40 + lane];
        acc += xv.z * LW[(4 * k4 + 2) * 40 + lane];
        acc += xv.w * LW[(4 * k4 + 3) * 40 + lane];
    }
    out[(size_t)wid * 40 + lane] = acc;
}

extern "C" void kernel_launch(void* const* d_in, const int* in_sizes, int n_in,
                              void* d_out, int out_size, void* d_ws, size_t ws_size,
                              hipStream_t stream) {
    const float* node_features = (const float*)d_in[0];
    const int*   edges         = (const int*)d_in[1];
    const float* edge_w        = (const float*)d_in[2];
    const int*   input_idx     = (const int*)d_in[3];
    const int N = in_sizes[0] / D;
    const int E = in_sizes[2];
    const int B = in_sizes[3];

    const float* P[6][6];
    for (int f = 0; f < 6; f++)
        for (int q = 0; q < 6; q++)
            P[f][q] = (const float*)d_in[4 + f * 6 + q];
    const float* logits_w = (const float*)d_in[40];
    const float* logits_b = (const float*)d_in[41];

    float* ws = (float*)d_ws;
    size_t nd = (size_t)N * D;
    float* xA  = ws;
    float* y   = ws + nd;
    float* red = ws + 2 * nd;
    float* p   = ws + 3 * nd;
    const int Ks[6] = {128, 128, 256, 128, 256, 128};
    float* Wt[6]; float* Bp[6];
    for (int f = 0; f < 6; f++) { Wt[f] = p; p += (size_t)Ks[f] * D; Bp[f] = p; p += D; }
    float* sums = p; // [0]=sum(edge_w), [1]=1/sum

    hipMemsetAsync(sums, 0, 2 * sizeof(float), stream);
    k_sum<<<512, 256, 0, stream>>>(edge_w, E, sums);
    k_recip<<<1, 1, 0, stream>>>(sums);
    for (int f = 0; f < 6; f++)
        k_fold<<<D, 256, 0, stream>>>(P[f][0], P[f][1], P[f][2], P[f][3], P[f][4], P[f][5],
                                      Wt[f], Bp[f], Ks[f]);

    const int gb = (N + 63) / 64;
    const int sb = (int)(((long long)E * 32 + 255) / 256);

    // pre
    k_ffn<128, false><<<gb, 256, 0, stream>>>(node_features, nullptr, Wt[0], Bp[0], nullptr, xA, N);
    // conv1: prepare per-node (ffn(x)[nbr] == ffn(x[nbr])), scatter, update+l2norm+residual
    k_ffn<128, false><<<gb, 256, 0, stream>>>(xA, nullptr, Wt[1], Bp[1], nullptr, y, N);
    hipMemsetAsync(red, 0, nd * sizeof(float), stream);
    k_scatter<<<sb, 256, 0, stream>>>(edges, edge_w, sums, y, red, E);
    k_ffn<256, true><<<gb, 256, 0, stream>>>(xA, red, Wt[2], Bp[2], xA, y, N);   // x1 -> y
    // conv2
    k_ffn<128, false><<<gb, 256, 0, stream>>>(y, nullptr, Wt[3], Bp[3], nullptr, xA, N);
    hipMemsetAsync(red, 0, nd * sizeof(float), stream);
    k_scatter<<<sb, 256, 0, stream>>>(edges, edge_w, sums, xA, red, E);
    k_ffn<256, true><<<gb, 256, 0, stream>>>(y, red, Wt[4], Bp[4], y, xA, N);    // x2 -> xA
    // post + logits
    k_ffn<128, false><<<gb, 256, 0, stream>>>(xA, nullptr, Wt[5], Bp[5], nullptr, y, N);
    k_logits<<<(B + 3) / 4, 256, 0, stream>>>(y, input_idx, logits_w, logits_b, (float*)d_out, B);
}

// Round 2
// 823.304 us; speedup vs baseline: 3.9109x; 3.9109x over previous
//
#include <hip/hip_runtime.h>
#include <math.h>

static constexpr int D = 128;
static constexpr float EPS_BN = 1e-3f;

__device__ __forceinline__ float gelu_exact(float x) {
    return 0.5f * x * (1.0f + erff(x * 0.70710678118654752f));
}

// ---------------- edge-weight sum ----------------
__global__ void k_sum(const float* __restrict__ w, int n, float* __restrict__ out) {
    float s = 0.f;
    for (int i = blockIdx.x * blockDim.x + threadIdx.x; i < n; i += gridDim.x * blockDim.x)
        s += w[i];
    for (int off = 32; off > 0; off >>= 1) s += __shfl_down(s, off, 64);
    __shared__ float sm[4];
    int lane = threadIdx.x & 63, wv = threadIdx.x >> 6;
    if (lane == 0) sm[wv] = s;
    __syncthreads();
    if (threadIdx.x == 0) atomicAdd(out, sm[0] + sm[1] + sm[2] + sm[3]);
}

__global__ void k_recip(float* s) { s[1] = 1.0f / s[0]; }

// ---------------- fold BN into weights ----------------
__global__ void k_fold(const float* __restrict__ g, const float* __restrict__ be,
                       const float* __restrict__ mu, const float* __restrict__ var,
                       const float* __restrict__ w, const float* __restrict__ bi,
                       float* __restrict__ wt, float* __restrict__ bp, int K) {
    int c = blockIdx.x; // 0..127
    float part = 0.f;
    for (int k = threadIdx.x; k < K; k += blockDim.x) {
        float a = g[k] / sqrtf(var[k] + EPS_BN);
        float wv = w[k * D + c];
        wt[c * K + k] = a * wv;
        part += (be[k] - mu[k] * a) * wv;
    }
    for (int off = 32; off > 0; off >>= 1) part += __shfl_down(part, off, 64);
    __shared__ float sm[4];
    int lane = threadIdx.x & 63, wv_ = threadIdx.x >> 6;
    if (lane == 0) sm[wv_] = part;
    __syncthreads();
    if (threadIdx.x == 0) bp[c] = bi[c] + sm[0] + sm[1] + sm[2] + sm[3];
}

// ---------------- CSR build ----------------
__global__ void k_hist(const int* __restrict__ edges, int* __restrict__ rowptr, int E) {
    int e = blockIdx.x * blockDim.x + threadIdx.x;
    if (e < E) atomicAdd(&rowptr[edges[e] + 1], 1);
}

// single-block inclusive scan in place over rowptr[0..N1-1]; pos[i]=result[i] for i<N1-1
__global__ void k_scan(int* __restrict__ rowptr, int* __restrict__ pos, int N1) {
    const int T = 1024;
    int t = threadIdx.x;
    int chunk = (N1 + T - 1) / T;
    int lo = t * chunk, hi = min(lo + chunk, N1);
    int s = 0;
    for (int i = lo; i < hi; i++) s += rowptr[i];
    __shared__ int sm[T];
    sm[t] = s;
    __syncthreads();
    for (int off = 1; off < T; off <<= 1) {
        int v = (t >= off) ? sm[t - off] : 0;
        __syncthreads();
        sm[t] += v;
        __syncthreads();
    }
    int run = (t > 0) ? sm[t - 1] : 0;
    for (int i = lo; i < hi; i++) {
        run += rowptr[i];
        rowptr[i] = run;
        if (i < N1 - 1) pos[i] = run;
    }
}

__global__ void k_fill(const int* __restrict__ edges, const float* __restrict__ ew,
                       const float* __restrict__ sums, int* __restrict__ pos,
                       int* __restrict__ col, float* __restrict__ wval, int E) {
    int e = blockIdx.x * blockDim.x + threadIdx.x;
    if (e >= E) return;
    int dst = edges[e], src = edges[E + e];
    int idx = atomicAdd(&pos[dst], 1);
    col[idx] = src;
    wval[idx] = ew[e] * sums[1];
}

// ---------------- CSR gather-reduce: red[n] = sum_e w[e]*y[col[e]]  (one wave/node)
__global__ void k_reduce(const int* __restrict__ rowptr, const int* __restrict__ col,
                         const float* __restrict__ wval, const float* __restrict__ y,
                         float* __restrict__ red, int N) {
    int n = blockIdx.x * (blockDim.x >> 6) + (threadIdx.x >> 6);
    if (n >= N) return;
    int lane = threadIdx.x & 63;
    int half = lane >> 5;    // 2 edges in flight
    int q = lane & 31;       // float4 slot
    int start = rowptr[n], end = rowptr[n + 1];
    float4 acc = {0.f, 0.f, 0.f, 0.f};
    int i = start + half;
    if (i < end) {
        int src = col[i];
        float w = wval[i];
        for (;;) {
            int ni = i + 2;
            int nsrc = 0; float nw = 0.f;
            if (ni < end) { nsrc = col[ni]; nw = wval[ni]; }
            float4 v = *((const float4*)(y + (size_t)src * D) + q);
            acc.x += w * v.x; acc.y += w * v.y; acc.z += w * v.z; acc.w += w * v.w;
            if (ni >= end) break;
            i = ni; src = nsrc; w = nw;
        }
    }
    acc.x += __shfl_xor(acc.x, 32, 64);
    acc.y += __shfl_xor(acc.y, 32, 64);
    acc.z += __shfl_xor(acc.z, 32, 64);
    acc.w += __shfl_xor(acc.w, 32, 64);
    if (half == 0)
        *((float4*)(red + (size_t)n * D) + q) = acc;
}

// ---------------- fused FFN GEMM: out = gelu(A @ W' + b'), optional l2norm+residual
template<int K, bool L2RES>
__global__ __launch_bounds__(256, 2) void k_ffn(
    const float* __restrict__ A0, const float* __restrict__ A1,
    const float* __restrict__ Wt, const float* __restrict__ bp,
    const float* __restrict__ resid, float* __restrict__ out, int nrows)
{
    constexpr int KC = 64;
    __shared__ float4 Alds[64 * 17];
    __shared__ float4 Wlds[128 * 16];

    const int tid = threadIdx.x;
    const int lane = tid & 63;
    const int wv = tid >> 6;
    const int lx = lane & 15;
    const int ly = lane >> 4;
    const int rowBlock = blockIdx.x * 64;
    const int swz = lx & 7;

    float acc[4][8];
    #pragma unroll
    for (int i = 0; i < 4; i++)
        #pragma unroll
        for (int j = 0; j < 8; j++) acc[i][j] = 0.f;

    for (int cc = 0; cc < K / KC; cc++) {
        const int k0 = cc * KC;
        const float* Asrc = (K == 256 && k0 >= 128) ? A1 : A0;
        const int kbase = (K == 256 && k0 >= 128) ? (k0 - 128) : k0;

        #pragma unroll
        for (int t = 0; t < 4; t++) {
            int i = tid + t * 256;
            int r = i >> 4, k4 = i & 15;
            int grow = rowBlock + r; if (grow >= nrows) grow = nrows - 1;
            Alds[r * 17 + k4] = *((const float4*)(Asrc + (size_t)grow * D + kbase) + k4);
        }
        #pragma unroll
        for (int t = 0; t < 8; t++) {
            int i = tid + t * 256;
            int c = i >> 4, k4 = i & 15;
            Wlds[c * 16 + (k4 ^ (c & 7))] = *((const float4*)Wt + c * (K / 4) + (k0 >> 2) + k4);
        }
        __syncthreads();

        #pragma unroll
        for (int k4 = 0; k4 < 16; k4++) {
            float4 a[4], w[8];
            #pragma unroll
            for (int i = 0; i < 4; i++)
                a[i] = Alds[(wv * 16 + ly * 4 + i) * 17 + k4];
            const int wk = k4 ^ swz;
            #pragma unroll
            for (int j = 0; j < 8; j++)
                w[j] = Wlds[(lx + 16 * j) * 16 + wk];
            #pragma unroll
            for (int i = 0; i < 4; i++)
                #pragma unroll
                for (int j = 0; j < 8; j++) {
                    acc[i][j] += a[i].x * w[j].x;
                    acc[i][j] += a[i].y * w[j].y;
                    acc[i][j] += a[i].z * w[j].z;
                    acc[i][j] += a[i].w * w[j].w;
                }
        }
        __syncthreads();
    }

    float bv[8];
    #pragma unroll
    for (int j = 0; j < 8; j++) bv[j] = bp[lx + 16 * j];

    #pragma unroll
    for (int i = 0; i < 4; i++) {
        int r = rowBlock + wv * 16 + ly * 4 + i;
        float g[8];
        #pragma unroll
        for (int j = 0; j < 8; j++) g[j] = gelu_exact(acc[i][j] + bv[j]);
        if (L2RES) {
            float ss = 0.f;
            #pragma unroll
            for (int j = 0; j < 8; j++) ss += g[j] * g[j];
            ss += __shfl_xor(ss, 1, 64);
            ss += __shfl_xor(ss, 2, 64);
            ss += __shfl_xor(ss, 4, 64);
            ss += __shfl_xor(ss, 8, 64);
            float inv = 1.0f / fmaxf(sqrtf(ss), 1e-12f);
            if (r < nrows) {
                #pragma unroll
                for (int j = 0; j < 8; j++)
                    out[(size_t)r * D + lx + 16 * j] = g[j] * inv + resid[(size_t)r * D + lx + 16 * j];
            }
        } else {
            if (r < nrows) {
                #pragma unroll
                for (int j = 0; j < 8; j++)
                    out[(size_t)r * D + lx + 16 * j] = g[j];
            }
        }
    }
}

// ---------------- gather + logits ----------------
__global__ void k_logits(const float* __restrict__ x, const int* __restrict__ idx,
                         const float* __restrict__ LW, const float* __restrict__ lb,
                         float* __restrict__ out, int B) {
    int wid = blockIdx.x * 4 + (threadIdx.x >> 6);
    int lane = threadIdx.x & 63;
    if (wid >= B) return;
    int row = __builtin_amdgcn_readfirstlane(idx[wid]);
    if (lane >= 40) return;
    float acc = lb[lane];
    const float4* xr = (const float4*)(x + (size_t)row * D);
    #pragma unroll 4
    for (int k4 = 0; k4 < 32; k4++) {
        float4 xv = xr[k4];
        acc += xv.x * LW[(4 * k4 + 0) * 40 + lane];
        acc += xv.y * LW[(4 * k4 + 1) * 40 + lane];
        acc += xv.z * LW[(4 * k4 + 2) * 40 + lane];
        acc += xv.w * LW[(4 * k4 + 3) * 40 + lane];
    }
    out[(size_t)wid * 40 + lane] = acc;
}

extern "C" void kernel_launch(void* const* d_in, const int* in_sizes, int n_in,
                              void* d_out, int out_size, void* d_ws, size_t ws_size,
                              hipStream_t stream) {
    const float* node_features = (const float*)d_in[0];
    const int*   edges         = (const int*)d_in[1];
    const float* edge_w        = (const float*)d_in[2];
    const int*   input_idx     = (const int*)d_in[3];
    const int N = in_sizes[0] / D;
    const int E = in_sizes[2];
    const int B = in_sizes[3];

    const float* P[6][6];
    for (int f = 0; f < 6; f++)
        for (int q = 0; q < 6; q++)
            P[f][q] = (const float*)d_in[4 + f * 6 + q];
    const float* logits_w = (const float*)d_in[40];
    const float* logits_b = (const float*)d_in[41];

    float* ws = (float*)d_ws;
    size_t nd = (size_t)N * D;
    float* xA  = ws;
    float* y   = ws + nd;
    float* red = ws + 2 * nd;
    float* p   = ws + 3 * nd;
    const int Ks[6] = {128, 128, 256, 128, 256, 128};
    float* Wt[6]; float* Bp[6];
    for (int f = 0; f < 6; f++) { Wt[f] = p; p += (size_t)Ks[f] * D; Bp[f] = p; p += D; }
    float* sums = p; p += 2;            // [0]=sum(edge_w), [1]=1/sum
    int* rowptr = (int*)p; p += (N + 1);
    int* pos    = (int*)p; p += N;
    int* col    = (int*)p; p += E;
    float* wval = p;       p += E;

    // edge-weight norm
    hipMemsetAsync(sums, 0, 2 * sizeof(float), stream);
    k_sum<<<512, 256, 0, stream>>>(edge_w, E, sums);
    k_recip<<<1, 1, 0, stream>>>(sums);

    // fold BN into weights
    for (int f = 0; f < 6; f++)
        k_fold<<<D, 256, 0, stream>>>(P[f][0], P[f][1], P[f][2], P[f][3], P[f][4], P[f][5],
                                      Wt[f], Bp[f], Ks[f]);

    // CSR build (shared by both convs)
    hipMemsetAsync(rowptr, 0, (size_t)(N + 1) * sizeof(int), stream);
    k_hist<<<(E + 255) / 256, 256, 0, stream>>>(edges, rowptr, E);
    k_scan<<<1, 1024, 0, stream>>>(rowptr, pos, N + 1);
    k_fill<<<(E + 255) / 256, 256, 0, stream>>>(edges, edge_w, sums, pos, col, wval, E);

    const int gb = (N + 63) / 64;
    const int rb = (N + 3) / 4;

    // pre
    k_ffn<128, false><<<gb, 256, 0, stream>>>(node_features, nullptr, Wt[0], Bp[0], nullptr, xA, N);
    // conv1
    k_ffn<128, false><<<gb, 256, 0, stream>>>(xA, nullptr, Wt[1], Bp[1], nullptr, y, N);
    k_reduce<<<rb, 256, 0, stream>>>(rowptr, col, wval, y, red, N);
    k_ffn<256, true><<<gb, 256, 0, stream>>>(xA, red, Wt[2], Bp[2], xA, y, N);   // x1 -> y
    // conv2
    k_ffn<128, false><<<gb, 256, 0, stream>>>(y, nullptr, Wt[3], Bp[3], nullptr, xA, N);
    k_reduce<<<rb, 256, 0, stream>>>(rowptr, col, wval, xA, red, N);
    k_ffn<256, true><<<gb, 256, 0, stream>>>(y, red, Wt[4], Bp[4], y, xA, N);    // x2 -> xA
    // post + logits
    k_ffn<128, false><<<gb, 256, 0, stream>>>(xA, nullptr, Wt[5], Bp[5], nullptr, y, N);
    k_logits<<<(B + 3) / 4, 256, 0, stream>>>(y, input_idx, logits_w, logits_b, (float*)d_out, B);
}

// Round 3
// 713.635 us; speedup vs baseline: 4.5119x; 1.1537x over previous
//
#include <hip/hip_runtime.h>
#include <math.h>

static constexpr int D = 128;
static constexpr float EPS_BN = 1e-3f;

__device__ __forceinline__ float gelu_exact(float x) {
    return 0.5f * x * (1.0f + erff(x * 0.70710678118654752f));
}

// ---------------- edge-weight sum ----------------
__global__ void k_sum(const float* __restrict__ w, int n, float* __restrict__ out) {
    float s = 0.f;
    for (int i = blockIdx.x * blockDim.x + threadIdx.x; i < n; i += gridDim.x * blockDim.x)
        s += w[i];
    for (int off = 32; off > 0; off >>= 1) s += __shfl_down(s, off, 64);
    __shared__ float sm[4];
    int lane = threadIdx.x & 63, wv = threadIdx.x >> 6;
    if (lane == 0) sm[wv] = s;
    __syncthreads();
    if (threadIdx.x == 0) atomicAdd(out, sm[0] + sm[1] + sm[2] + sm[3]);
}

__global__ void k_recip(float* s) { s[1] = 1.0f / s[0]; }

// ---------------- fold BN into weights (all 6 FFNs in one launch) ----------------
struct FoldArgs {
    const float* g[6]; const float* be[6]; const float* mu[6];
    const float* var[6]; const float* w[6]; const float* bi[6];
    float* wt[6]; float* bp[6]; int K[6];
};

__global__ void k_fold_all(FoldArgs fa) {
    const int f = blockIdx.y;
    const int c = blockIdx.x; // 0..127
    const int K = fa.K[f];
    const float* g = fa.g[f]; const float* be = fa.be[f];
    const float* mu = fa.mu[f]; const float* var = fa.var[f];
    const float* w = fa.w[f]; const float* bi = fa.bi[f];
    float* wt = fa.wt[f]; float* bp = fa.bp[f];
    float part = 0.f;
    for (int k = threadIdx.x; k < K; k += blockDim.x) {
        float a = g[k] / sqrtf(var[k] + EPS_BN);
        float wv = w[k * D + c];
        wt[c * K + k] = a * wv;
        part += (be[k] - mu[k] * a) * wv;
    }
    for (int off = 32; off > 0; off >>= 1) part += __shfl_down(part, off, 64);
    __shared__ float sm[4];
    int lane = threadIdx.x & 63, wv_ = threadIdx.x >> 6;
    if (lane == 0) sm[wv_] = part;
    __syncthreads();
    if (threadIdx.x == 0) bp[c] = bi[c] + sm[0] + sm[1] + sm[2] + sm[3];
}

// ---------------- CSR build ----------------
__global__ void k_hist(const int* __restrict__ edges, int* __restrict__ cnt, int E) {
    int e = blockIdx.x * blockDim.x + threadIdx.x;
    if (e < E) atomicAdd(&cnt[edges[e]], 1);
}

// pass 1: per-block exclusive scan of cnt -> rowptr (block-local), block sums -> bsum
__global__ void k_scan1(const int* __restrict__ cnt, int* __restrict__ rowptr,
                        int* __restrict__ bsum, int N) {
    __shared__ int sm[1024];
    int t = threadIdx.x;
    int i = blockIdx.x * 1024 + t;
    int c = (i < N) ? cnt[i] : 0;
    sm[t] = c;
    __syncthreads();
    #pragma unroll
    for (int off = 1; off < 1024; off <<= 1) {
        int v = (t >= off) ? sm[t - off] : 0;
        __syncthreads();
        sm[t] += v;
        __syncthreads();
    }
    if (i < N) rowptr[i] = sm[t] - c; // block-local exclusive
    if (t == 1023) bsum[blockIdx.x] = sm[1023];
}

// pass 2: single wave scans block sums (nb <= 64), writes rowptr[N] = E
__global__ void k_scan2(int* __restrict__ bsum, int* __restrict__ bpre,
                        int* __restrict__ rowptr, int nb, int N) {
    int lane = threadIdx.x;
    int v = (lane < nb) ? bsum[lane] : 0;
    #pragma unroll
    for (int off = 1; off < 64; off <<= 1) {
        int u = __shfl_up(v, off, 64);
        if (lane >= off) v += u;
    }
    if (lane < nb) bpre[lane] = v;
    if (lane == nb - 1) rowptr[N] = v;
}

// pass 3: add block prefix, write pos
__global__ void k_scan3(int* __restrict__ rowptr, int* __restrict__ pos,
                        const int* __restrict__ bpre, int N) {
    int i = blockIdx.x * 1024 + threadIdx.x;
    if (i >= N) return;
    int off = (blockIdx.x > 0) ? bpre[blockIdx.x - 1] : 0;
    int r = rowptr[i] + off;
    rowptr[i] = r;
    pos[i] = r;
}

__global__ void k_fill(const int* __restrict__ edges, const float* __restrict__ ew,
                       const float* __restrict__ sums, int* __restrict__ pos,
                       int* __restrict__ col, float* __restrict__ wval, int E) {
    int e = blockIdx.x * blockDim.x + threadIdx.x;
    if (e >= E) return;
    int dst = edges[e], src = edges[E + e];
    int idx = atomicAdd(&pos[dst], 1);
    col[idx] = src;
    wval[idx] = ew[e] * sums[1];
}

// ---------------- CSR gather-reduce: red[n] = sum_e w[e]*y[col[e]]  (one wave/node)
__global__ void k_reduce(const int* __restrict__ rowptr, const int* __restrict__ col,
                         const float* __restrict__ wval, const float* __restrict__ y,
                         float* __restrict__ red, int N) {
    int n = blockIdx.x * (blockDim.x >> 6) + (threadIdx.x >> 6);
    if (n >= N) return;
    int lane = threadIdx.x & 63;
    int half = lane >> 5;    // 2 edges in flight
    int q = lane & 31;       // float4 slot
    int start = rowptr[n], end = rowptr[n + 1];
    float4 acc = {0.f, 0.f, 0.f, 0.f};
    int i = start + half;
    if (i < end) {
        int src = col[i];
        float w = wval[i];
        for (;;) {
            int ni = i + 2;
            int nsrc = 0; float nw = 0.f;
            if (ni < end) { nsrc = col[ni]; nw = wval[ni]; }
            float4 v = *((const float4*)(y + (size_t)src * D) + q);
            acc.x += w * v.x; acc.y += w * v.y; acc.z += w * v.z; acc.w += w * v.w;
            if (ni >= end) break;
            i = ni; src = nsrc; w = nw;
        }
    }
    acc.x += __shfl_xor(acc.x, 32, 64);
    acc.y += __shfl_xor(acc.y, 32, 64);
    acc.z += __shfl_xor(acc.z, 32, 64);
    acc.w += __shfl_xor(acc.w, 32, 64);
    if (half == 0)
        *((float4*)(red + (size_t)n * D) + q) = acc;
}

// ---------------- fused FFN GEMM: out = gelu(A @ W' + b'), optional l2norm+residual
template<int K, bool L2RES>
__global__ __launch_bounds__(256, 2) void k_ffn(
    const float* __restrict__ A0, const float* __restrict__ A1,
    const float* __restrict__ Wt, const float* __restrict__ bp,
    const float* __restrict__ resid, float* __restrict__ out, int nrows)
{
    constexpr int KC = 64;
    __shared__ float4 Alds[64 * 17];
    __shared__ float4 Wlds[128 * 16];

    const int tid = threadIdx.x;
    const int lane = tid & 63;
    const int wv = tid >> 6;
    const int lx = lane & 15;
    const int ly = lane >> 4;
    const int rowBlock = blockIdx.x * 64;
    const int swz = lx & 7;

    float acc[4][8];
    #pragma unroll
    for (int i = 0; i < 4; i++)
        #pragma unroll
        for (int j = 0; j < 8; j++) acc[i][j] = 0.f;

    for (int cc = 0; cc < K / KC; cc++) {
        const int k0 = cc * KC;
        const float* Asrc = (K == 256 && k0 >= 128) ? A1 : A0;
        const int kbase = (K == 256 && k0 >= 128) ? (k0 - 128) : k0;

        #pragma unroll
        for (int t = 0; t < 4; t++) {
            int i = tid + t * 256;
            int r = i >> 4, k4 = i & 15;
            int grow = rowBlock + r; if (grow >= nrows) grow = nrows - 1;
            Alds[r * 17 + k4] = *((const float4*)(Asrc + (size_t)grow * D + kbase) + k4);
        }
        #pragma unroll
        for (int t = 0; t < 8; t++) {
            int i = tid + t * 256;
            int c = i >> 4, k4 = i & 15;
            Wlds[c * 16 + (k4 ^ (c & 7))] = *((const float4*)Wt + c * (K / 4) + (k0 >> 2) + k4);
        }
        __syncthreads();

        #pragma unroll
        for (int k4 = 0; k4 < 16; k4++) {
            float4 a[4], w[8];
            #pragma unroll
            for (int i = 0; i < 4; i++)
                a[i] = Alds[(wv * 16 + ly * 4 + i) * 17 + k4];
            const int wk = k4 ^ swz;
            #pragma unroll
            for (int j = 0; j < 8; j++)
                w[j] = Wlds[(lx + 16 * j) * 16 + wk];
            #pragma unroll
            for (int i = 0; i < 4; i++)
                #pragma unroll
                for (int j = 0; j < 8; j++) {
                    acc[i][j] += a[i].x * w[j].x;
                    acc[i][j] += a[i].y * w[j].y;
                    acc[i][j] += a[i].z * w[j].z;
                    acc[i][j] += a[i].w * w[j].w;
                }
        }
        __syncthreads();
    }

    float bv[8];
    #pragma unroll
    for (int j = 0; j < 8; j++) bv[j] = bp[lx + 16 * j];

    #pragma unroll
    for (int i = 0; i < 4; i++) {
        int r = rowBlock + wv * 16 + ly * 4 + i;
        float g[8];
        #pragma unroll
        for (int j = 0; j < 8; j++) g[j] = gelu_exact(acc[i][j] + bv[j]);
        if (L2RES) {
            float ss = 0.f;
            #pragma unroll
            for (int j = 0; j < 8; j++) ss += g[j] * g[j];
            ss += __shfl_xor(ss, 1, 64);
            ss += __shfl_xor(ss, 2, 64);
            ss += __shfl_xor(ss, 4, 64);
            ss += __shfl_xor(ss, 8, 64);
            float inv = 1.0f / fmaxf(sqrtf(ss), 1e-12f);
            if (r < nrows) {
                #pragma unroll
                for (int j = 0; j < 8; j++)
                    out[(size_t)r * D + lx + 16 * j] = g[j] * inv + resid[(size_t)r * D + lx + 16 * j];
            }
        } else {
            if (r < nrows) {
                #pragma unroll
                for (int j = 0; j < 8; j++)
                    out[(size_t)r * D + lx + 16 * j] = g[j];
            }
        }
    }
}

// ---------------- gather + logits ----------------
__global__ void k_logits(const float* __restrict__ x, const int* __restrict__ idx,
                         const float* __restrict__ LW, const float* __restrict__ lb,
                         float* __restrict__ out, int B) {
    int wid = blockIdx.x * 4 + (threadIdx.x >> 6);
    int lane = threadIdx.x & 63;
    if (wid >= B) return;
    int row = __builtin_amdgcn_readfirstlane(idx[wid]);
    if (lane >= 40) return;
    float acc = lb[lane];
    const float4* xr = (const float4*)(x + (size_t)row * D);
    #pragma unroll 4
    for (int k4 = 0; k4 < 32; k4++) {
        float4 xv = xr[k4];
        acc += xv.x * LW[(4 * k4 + 0) * 40 + lane];
        acc += xv.y * LW[(4 * k4 + 1) * 40 + lane];
        acc += xv.z * LW[(4 * k4 + 2) * 40 + lane];
        acc += xv.w * LW[(4 * k4 + 3) * 40 + lane];
    }
    out[(size_t)wid * 40 + lane] = acc;
}

extern "C" void kernel_launch(void* const* d_in, const int* in_sizes, int n_in,
                              void* d_out, int out_size, void* d_ws, size_t ws_size,
                              hipStream_t stream) {
    const float* node_features = (const float*)d_in[0];
    const int*   edges         = (const int*)d_in[1];
    const float* edge_w        = (const float*)d_in[2];
    const int*   input_idx     = (const int*)d_in[3];
    const int N = in_sizes[0] / D;
    const int E = in_sizes[2];
    const int B = in_sizes[3];

    const float* P[6][6];
    for (int f = 0; f < 6; f++)
        for (int q = 0; q < 6; q++)
            P[f][q] = (const float*)d_in[4 + f * 6 + q];
    const float* logits_w = (const float*)d_in[40];
    const float* logits_b = (const float*)d_in[41];

    float* ws = (float*)d_ws;
    size_t nd = (size_t)N * D;
    float* xA  = ws;
    float* y   = ws + nd;
    float* red = ws + 2 * nd;
    float* p   = ws + 3 * nd;
    const int Ks[6] = {128, 128, 256, 128, 256, 128};
    float* Wt[6]; float* Bp[6];
    for (int f = 0; f < 6; f++) { Wt[f] = p; p += (size_t)Ks[f] * D; Bp[f] = p; p += D; }
    float* sums = p; p += 2;            // [0]=sum(edge_w), [1]=1/sum
    int* rowptr = (int*)p; p += (N + 1);
    int* pos    = (int*)p; p += N;
    int* cnt    = (int*)p; p += N;
    int* bsum   = (int*)p; p += 64;
    int* bpre   = (int*)p; p += 64;
    int* col    = (int*)p; p += E;
    float* wval = p;       p += E;

    // edge-weight norm
    hipMemsetAsync(sums, 0, 2 * sizeof(float), stream);
    k_sum<<<512, 256, 0, stream>>>(edge_w, E, sums);
    k_recip<<<1, 1, 0, stream>>>(sums);

    // fold BN into weights (single launch)
    FoldArgs fa;
    for (int f = 0; f < 6; f++) {
        fa.g[f] = P[f][0]; fa.be[f] = P[f][1]; fa.mu[f] = P[f][2];
        fa.var[f] = P[f][3]; fa.w[f] = P[f][4]; fa.bi[f] = P[f][5];
        fa.wt[f] = Wt[f]; fa.bp[f] = Bp[f]; fa.K[f] = Ks[f];
    }
    k_fold_all<<<dim3(D, 6), 256, 0, stream>>>(fa);

    // CSR build (shared by both convs)
    const int nb = (N + 1023) / 1024;
    hipMemsetAsync(cnt, 0, (size_t)N * sizeof(int), stream);
    k_hist<<<(E + 255) / 256, 256, 0, stream>>>(edges, cnt, E);
    k_scan1<<<nb, 1024, 0, stream>>>(cnt, rowptr, bsum, N);
    k_scan2<<<1, 64, 0, stream>>>(bsum, bpre, rowptr, nb, N);
    k_scan3<<<nb, 1024, 0, stream>>>(rowptr, pos, bpre, N);
    k_fill<<<(E + 255) / 256, 256, 0, stream>>>(edges, edge_w, sums, pos, col, wval, E);

    const int gb = (N + 63) / 64;
    const int rb = (N + 3) / 4;

    // pre
    k_ffn<128, false><<<gb, 256, 0, stream>>>(node_features, nullptr, Wt[0], Bp[0], nullptr, xA, N);
    // conv1
    k_ffn<128, false><<<gb, 256, 0, stream>>>(xA, nullptr, Wt[1], Bp[1], nullptr, y, N);
    k_reduce<<<rb, 256, 0, stream>>>(rowptr, col, wval, y, red, N);
    k_ffn<256, true><<<gb, 256, 0, stream>>>(xA, red, Wt[2], Bp[2], xA, y, N);   // x1 -> y
    // conv2
    k_ffn<128, false><<<gb, 256, 0, stream>>>(y, nullptr, Wt[3], Bp[3], nullptr, xA, N);
    k_reduce<<<rb, 256, 0, stream>>>(rowptr, col, wval, xA, red, N);
    k_ffn<256, true><<<gb, 256, 0, stream>>>(y, red, Wt[4], Bp[4], y, xA, N);    // x2 -> xA
    // post + logits
    k_ffn<128, false><<<gb, 256, 0, stream>>>(xA, nullptr, Wt[5], Bp[5], nullptr, y, N);
    k_logits<<<(B + 3) / 4, 256, 0, stream>>>(y, input_idx, logits_w, logits_b, (float*)d_out, B);
}

// Round 4
// 539.046 us; speedup vs baseline: 5.9732x; 1.3239x over previous
//
#include <hip/hip_runtime.h>
#include <math.h>

static constexpr int D = 128;
static constexpr float EPS_BN = 1e-3f;

typedef short short8 __attribute__((ext_vector_type(8)));
typedef short short4v __attribute__((ext_vector_type(4)));
typedef float float4v __attribute__((ext_vector_type(4)));

__device__ __forceinline__ float gelu_exact(float x) {
    return 0.5f * x * (1.0f + erff(x * 0.70710678118654752f));
}

// split fp32 into bf16 hi (truncate) + bf16 lo (truncate of remainder): x ~ hi + lo, err ~2^-17
__device__ __forceinline__ void f32_to_hilo(float f, short& h, short& l) {
    unsigned u = __float_as_uint(f);
    h = (short)(u >> 16);
    float hf = __uint_as_float(u & 0xFFFF0000u);
    unsigned lu = __float_as_uint(f - hf);
    l = (short)(lu >> 16);
}

// ---------------- edge-weight sum ----------------
__global__ void k_sum(const float* __restrict__ w, int n, float* __restrict__ out) {
    float s = 0.f;
    for (int i = blockIdx.x * blockDim.x + threadIdx.x; i < n; i += gridDim.x * blockDim.x)
        s += w[i];
    for (int off = 32; off > 0; off >>= 1) s += __shfl_down(s, off, 64);
    __shared__ float sm[4];
    int lane = threadIdx.x & 63, wv = threadIdx.x >> 6;
    if (lane == 0) sm[wv] = s;
    __syncthreads();
    if (threadIdx.x == 0) atomicAdd(out, sm[0] + sm[1] + sm[2] + sm[3]);
}

__global__ void k_recip(float* s) { s[1] = 1.0f / s[0]; }

// ---------------- fold BN into weights, pre-split to bf16 hi/lo ----------------
struct FoldArgs {
    const float* g[6]; const float* be[6]; const float* mu[6];
    const float* var[6]; const float* w[6]; const float* bi[6];
    short* wh[6]; short* wl[6]; float* bp[6]; int K[6];
};

__global__ void k_fold_all(FoldArgs fa) {
    const int f = blockIdx.y;
    const int c = blockIdx.x; // 0..127
    const int K = fa.K[f];
    const float* g = fa.g[f]; const float* be = fa.be[f];
    const float* mu = fa.mu[f]; const float* var = fa.var[f];
    const float* w = fa.w[f]; const float* bi = fa.bi[f];
    short* wh = fa.wh[f]; short* wl = fa.wl[f]; float* bp = fa.bp[f];
    float part = 0.f;
    for (int k = threadIdx.x; k < K; k += blockDim.x) {
        float a = g[k] / sqrtf(var[k] + EPS_BN);
        float wv = w[k * D + c];
        float prod = a * wv;
        short hh, ll;
        f32_to_hilo(prod, hh, ll);
        wh[c * K + k] = hh;
        wl[c * K + k] = ll;
        part += (be[k] - mu[k] * a) * wv;
    }
    for (int off = 32; off > 0; off >>= 1) part += __shfl_down(part, off, 64);
    __shared__ float sm[4];
    int lane = threadIdx.x & 63, wv_ = threadIdx.x >> 6;
    if (lane == 0) sm[wv_] = part;
    __syncthreads();
    if (threadIdx.x == 0) bp[c] = bi[c] + sm[0] + sm[1] + sm[2] + sm[3];
}

// ---------------- CSR build ----------------
__global__ void k_hist(const int* __restrict__ edges, int* __restrict__ cnt, int E) {
    int e = blockIdx.x * blockDim.x + threadIdx.x;
    if (e < E) atomicAdd(&cnt[edges[e]], 1);
}

__global__ void k_scan1(const int* __restrict__ cnt, int* __restrict__ rowptr,
                        int* __restrict__ bsum, int N) {
    __shared__ int sm[1024];
    int t = threadIdx.x;
    int i = blockIdx.x * 1024 + t;
    int c = (i < N) ? cnt[i] : 0;
    sm[t] = c;
    __syncthreads();
    #pragma unroll
    for (int off = 1; off < 1024; off <<= 1) {
        int v = (t >= off) ? sm[t - off] : 0;
        __syncthreads();
        sm[t] += v;
        __syncthreads();
    }
    if (i < N) rowptr[i] = sm[t] - c;
    if (t == 1023) bsum[blockIdx.x] = sm[1023];
}

__global__ void k_scan2(int* __restrict__ bsum, int* __restrict__ bpre,
                        int* __restrict__ rowptr, int nb, int N) {
    int lane = threadIdx.x;
    int v = (lane < nb) ? bsum[lane] : 0;
    #pragma unroll
    for (int off = 1; off < 64; off <<= 1) {
        int u = __shfl_up(v, off, 64);
        if (lane >= off) v += u;
    }
    if (lane < nb) bpre[lane] = v;
    if (lane == nb - 1) rowptr[N] = v;
}

__global__ void k_scan3(int* __restrict__ rowptr, int* __restrict__ pos,
                        const int* __restrict__ bpre, int N) {
    int i = blockIdx.x * 1024 + threadIdx.x;
    if (i >= N) return;
    int off = (blockIdx.x > 0) ? bpre[blockIdx.x - 1] : 0;
    int r = rowptr[i] + off;
    rowptr[i] = r;
    pos[i] = r;
}

__global__ void k_fill(const int* __restrict__ edges, const float* __restrict__ ew,
                       const float* __restrict__ sums, int* __restrict__ pos,
                       int* __restrict__ col, float* __restrict__ wval, int E) {
    int e = blockIdx.x * blockDim.x + threadIdx.x;
    if (e >= E) return;
    int dst = edges[e], src = edges[E + e];
    int idx = atomicAdd(&pos[dst], 1);
    col[idx] = src;
    wval[idx] = ew[e] * sums[1];
}

// ---------------- CSR gather-reduce: red[n] = sum_e w[e]*y[col[e]]  (one wave/node)
__global__ void k_reduce(const int* __restrict__ rowptr, const int* __restrict__ col,
                         const float* __restrict__ wval, const float* __restrict__ y,
                         float* __restrict__ red, int N) {
    int n = blockIdx.x * (blockDim.x >> 6) + (threadIdx.x >> 6);
    if (n >= N) return;
    int lane = threadIdx.x & 63;
    int half = lane >> 5;
    int q = lane & 31;
    int start = rowptr[n], end = rowptr[n + 1];
    float4 acc = {0.f, 0.f, 0.f, 0.f};
    int i = start + half;
    if (i < end) {
        int src = col[i];
        float w = wval[i];
        for (;;) {
            int ni = i + 2;
            int nsrc = 0; float nw = 0.f;
            if (ni < end) { nsrc = col[ni]; nw = wval[ni]; }
            float4 v = *((const float4*)(y + (size_t)src * D) + q);
            acc.x += w * v.x; acc.y += w * v.y; acc.z += w * v.z; acc.w += w * v.w;
            if (ni >= end) break;
            i = ni; src = nsrc; w = nw;
        }
    }
    acc.x += __shfl_xor(acc.x, 32, 64);
    acc.y += __shfl_xor(acc.y, 32, 64);
    acc.z += __shfl_xor(acc.z, 32, 64);
    acc.w += __shfl_xor(acc.w, 32, 64);
    if (half == 0)
        *((float4*)(red + (size_t)n * D) + q) = acc;
}

// ---------------- split-bf16 MFMA FFN: out = gelu(A @ W' + b'), optional l2norm+residual
// Block tile 128 rows x 128 cols, 4 waves in 2x2, each wave 4x4 grid of 16x16 MFMA tiles.
// X@W ~= Xh@Wh + Xh@Wl + Xl@Wh  (fp32 accumulate)
template<int K, bool L2RES>
__global__ __launch_bounds__(256, 2) void k_ffn(
    const float* __restrict__ A0, const float* __restrict__ A1,
    const short* __restrict__ Wh, const short* __restrict__ Wl,
    const float* __restrict__ bp, const float* __restrict__ resid,
    float* __restrict__ out, int nrows)
{
    __shared__ short Abuf[2][128][72];   // [hi/lo][row][k] stride 72 -> balanced bank groups
    __shared__ short Wbuf[2][128][72];   // [hi/lo][col][k]
    __shared__ float rs[128][2];         // row sumsq partials per wave-col

    const int tid = threadIdx.x;
    const int lane = tid & 63;
    const int wv = tid >> 6;
    const int wr = wv >> 1;   // wave row 0..1
    const int wc = wv & 1;    // wave col 0..1
    const int m = lane & 15;
    const int quad = lane >> 4;
    const int rowBlock = blockIdx.x * 128;

    float4v acc[4][4];
    #pragma unroll
    for (int ti = 0; ti < 4; ti++)
        #pragma unroll
        for (int tj = 0; tj < 4; tj++)
            acc[ti][tj] = (float4v){0.f, 0.f, 0.f, 0.f};

    for (int cc = 0; cc < K / 64; cc++) {
        const float* Asrc = (K == 256 && cc >= 2) ? A1 : A0;
        const int kb = (K == 256) ? ((cc & 1) * 64) : (cc * 64);  // offset within source (stride D)
        const int kw = cc * 64;                                    // offset within W's K dim

        // stage A: 128 rows x 64 k fp32 -> bf16 hi/lo  (2048 float4 granules)
        #pragma unroll
        for (int t = 0; t < 8; t++) {
            int i = tid + t * 256;
            int r = i >> 4, k4 = i & 15;
            int grow = rowBlock + r; if (grow >= nrows) grow = nrows - 1;
            float4 f = *((const float4*)(Asrc + (size_t)grow * D + kb) + k4);
            short h0, l0, h1, l1, h2, l2, h3, l3;
            f32_to_hilo(f.x, h0, l0);
            f32_to_hilo(f.y, h1, l1);
            f32_to_hilo(f.z, h2, l2);
            f32_to_hilo(f.w, h3, l3);
            short4v hh = {h0, h1, h2, h3};
            short4v ll = {l0, l1, l2, l3};
            *(short4v*)&Abuf[0][r][k4 * 4] = hh;
            *(short4v*)&Abuf[1][r][k4 * 4] = ll;
        }
        // stage W: 128 cols x 64 k bf16 hi/lo (preconverted)  (1024 granules of 8 shorts)
        #pragma unroll
        for (int t = 0; t < 4; t++) {
            int i = tid + t * 256;
            int c = i >> 3, g = i & 7;
            short8 wh8 = *(const short8*)(Wh + (size_t)c * K + kw + g * 8);
            short8 wl8 = *(const short8*)(Wl + (size_t)c * K + kw + g * 8);
            *(short8*)&Wbuf[0][c][g * 8] = wh8;
            *(short8*)&Wbuf[1][c][g * 8] = wl8;
        }
        __syncthreads();

        #pragma unroll
        for (int ks = 0; ks < 2; ks++) {
            short8 ah[4], al[4], bh[4], bl[4];
            #pragma unroll
            for (int ti = 0; ti < 4; ti++) {
                ah[ti] = *(const short8*)&Abuf[0][wr * 64 + ti * 16 + m][ks * 32 + quad * 8];
                al[ti] = *(const short8*)&Abuf[1][wr * 64 + ti * 16 + m][ks * 32 + quad * 8];
            }
            #pragma unroll
            for (int tj = 0; tj < 4; tj++) {
                bh[tj] = *(const short8*)&Wbuf[0][wc * 64 + tj * 16 + m][ks * 32 + quad * 8];
                bl[tj] = *(const short8*)&Wbuf[1][wc * 64 + tj * 16 + m][ks * 32 + quad * 8];
            }
            #pragma unroll
            for (int ti = 0; ti < 4; ti++)
                #pragma unroll
                for (int tj = 0; tj < 4; tj++) {
                    acc[ti][tj] = __builtin_amdgcn_mfma_f32_16x16x32_bf16(al[ti], bh[tj], acc[ti][tj], 0, 0, 0);
                    acc[ti][tj] = __builtin_amdgcn_mfma_f32_16x16x32_bf16(ah[ti], bl[tj], acc[ti][tj], 0, 0, 0);
                    acc[ti][tj] = __builtin_amdgcn_mfma_f32_16x16x32_bf16(ah[ti], bh[tj], acc[ti][tj], 0, 0, 0);
                }
        }
        __syncthreads();
    }

    // epilogue: bias + gelu (+ l2norm + residual)
    float bvv[4];
    #pragma unroll
    for (int tj = 0; tj < 4; tj++) bvv[tj] = bp[wc * 64 + tj * 16 + m];

    float g[4][4][4];
    #pragma unroll
    for (int ti = 0; ti < 4; ti++)
        #pragma unroll
        for (int tj = 0; tj < 4; tj++)
            #pragma unroll
            for (int r4 = 0; r4 < 4; r4++)
                g[ti][tj][r4] = gelu_exact(acc[ti][tj][r4] + bvv[tj]);

    if (L2RES) {
        #pragma unroll
        for (int ti = 0; ti < 4; ti++)
            #pragma unroll
            for (int r4 = 0; r4 < 4; r4++) {
                float ss = 0.f;
                #pragma unroll
                for (int tj = 0; tj < 4; tj++) ss += g[ti][tj][r4] * g[ti][tj][r4];
                ss += __shfl_xor(ss, 1, 64);
                ss += __shfl_xor(ss, 2, 64);
                ss += __shfl_xor(ss, 4, 64);
                ss += __shfl_xor(ss, 8, 64);
                if (m == 0) rs[wr * 64 + ti * 16 + quad * 4 + r4][wc] = ss;
            }
        __syncthreads();
        #pragma unroll
        for (int ti = 0; ti < 4; ti++)
            #pragma unroll
            for (int r4 = 0; r4 < 4; r4++) {
                int rib = wr * 64 + ti * 16 + quad * 4 + r4;
                float tot = rs[rib][0] + rs[rib][1];
                float inv = 1.0f / fmaxf(sqrtf(tot), 1e-12f);
                int row = rowBlock + rib;
                if (row < nrows) {
                    #pragma unroll
                    for (int tj = 0; tj < 4; tj++) {
                        int c = wc * 64 + tj * 16 + m;
                        out[(size_t)row * D + c] = g[ti][tj][r4] * inv + resid[(size_t)row * D + c];
                    }
                }
            }
    } else {
        #pragma unroll
        for (int ti = 0; ti < 4; ti++)
            #pragma unroll
            for (int r4 = 0; r4 < 4; r4++) {
                int row = rowBlock + wr * 64 + ti * 16 + quad * 4 + r4;
                if (row < nrows) {
                    #pragma unroll
                    for (int tj = 0; tj < 4; tj++) {
                        int c = wc * 64 + tj * 16 + m;
                        out[(size_t)row * D + c] = g[ti][tj][r4];
                    }
                }
            }
    }
}

// ---------------- gather + logits ----------------
__global__ void k_logits(const float* __restrict__ x, const int* __restrict__ idx,
                         const float* __restrict__ LW, const float* __restrict__ lb,
                         float* __restrict__ out, int B) {
    int wid = blockIdx.x * 4 + (threadIdx.x >> 6);
    int lane = threadIdx.x & 63;
    if (wid >= B) return;
    int row = __builtin_amdgcn_readfirstlane(idx[wid]);
    if (lane >= 40) return;
    float acc = lb[lane];
    const float4* xr = (const float4*)(x + (size_t)row * D);
    #pragma unroll 4
    for (int k4 = 0; k4 < 32; k4++) {
        float4 xv = xr[k4];
        acc += xv.x * LW[(4 * k4 + 0) * 40 + lane];
        acc += xv.y * LW[(4 * k4 + 1) * 40 + lane];
        acc += xv.z * LW[(4 * k4 + 2) * 40 + lane];
        acc += xv.w * LW[(4 * k4 + 3) * 40 + lane];
    }
    out[(size_t)wid * 40 + lane] = acc;
}

extern "C" void kernel_launch(void* const* d_in, const int* in_sizes, int n_in,
                              void* d_out, int out_size, void* d_ws, size_t ws_size,
                              hipStream_t stream) {
    const float* node_features = (const float*)d_in[0];
    const int*   edges         = (const int*)d_in[1];
    const float* edge_w        = (const float*)d_in[2];
    const int*   input_idx     = (const int*)d_in[3];
    const int N = in_sizes[0] / D;
    const int E = in_sizes[2];
    const int B = in_sizes[3];

    const float* P[6][6];
    for (int f = 0; f < 6; f++)
        for (int q = 0; q < 6; q++)
            P[f][q] = (const float*)d_in[4 + f * 6 + q];
    const float* logits_w = (const float*)d_in[40];
    const float* logits_b = (const float*)d_in[41];

    float* ws = (float*)d_ws;
    size_t nd = (size_t)N * D;
    float* xA  = ws;
    float* y   = ws + nd;
    float* red = ws + 2 * nd;
    float* p   = ws + 3 * nd;
    const int Ks[6] = {128, 128, 256, 128, 256, 128};
    short* Wh[6]; short* Wl[6]; float* Bp[6];
    {
        short* sp = (short*)p;
        for (int f = 0; f < 6; f++) {
            Wh[f] = sp; sp += (size_t)Ks[f] * D;
            Wl[f] = sp; sp += (size_t)Ks[f] * D;
        }
        p = (float*)sp;
    }
    for (int f = 0; f < 6; f++) { Bp[f] = p; p += D; }
    float* sums = p; p += 2;
    int* rowptr = (int*)p; p += (N + 1);
    int* pos    = (int*)p; p += N;
    int* cnt    = (int*)p; p += N;
    int* bsum   = (int*)p; p += 64;
    int* bpre   = (int*)p; p += 64;
    int* col    = (int*)p; p += E;
    float* wval = p;       p += E;

    // edge-weight norm
    hipMemsetAsync(sums, 0, 2 * sizeof(float), stream);
    k_sum<<<512, 256, 0, stream>>>(edge_w, E, sums);
    k_recip<<<1, 1, 0, stream>>>(sums);

    // fold BN into weights, split to bf16 hi/lo
    FoldArgs fa;
    for (int f = 0; f < 6; f++) {
        fa.g[f] = P[f][0]; fa.be[f] = P[f][1]; fa.mu[f] = P[f][2];
        fa.var[f] = P[f][3]; fa.w[f] = P[f][4]; fa.bi[f] = P[f][5];
        fa.wh[f] = Wh[f]; fa.wl[f] = Wl[f]; fa.bp[f] = Bp[f]; fa.K[f] = Ks[f];
    }
    k_fold_all<<<dim3(D, 6), 256, 0, stream>>>(fa);

    // CSR build (shared by both convs)
    const int nb = (N + 1023) / 1024;
    hipMemsetAsync(cnt, 0, (size_t)N * sizeof(int), stream);
    k_hist<<<(E + 255) / 256, 256, 0, stream>>>(edges, cnt, E);
    k_scan1<<<nb, 1024, 0, stream>>>(cnt, rowptr, bsum, N);
    k_scan2<<<1, 64, 0, stream>>>(bsum, bpre, rowptr, nb, N);
    k_scan3<<<nb, 1024, 0, stream>>>(rowptr, pos, bpre, N);
    k_fill<<<(E + 255) / 256, 256, 0, stream>>>(edges, edge_w, sums, pos, col, wval, E);

    const int gb = (N + 127) / 128;
    const int rb = (N + 3) / 4;

    // pre
    k_ffn<128, false><<<gb, 256, 0, stream>>>(node_features, nullptr, Wh[0], Wl[0], Bp[0], nullptr, xA, N);
    // conv1: prepare per-node, CSR reduce, update+l2norm+residual
    k_ffn<128, false><<<gb, 256, 0, stream>>>(xA, nullptr, Wh[1], Wl[1], Bp[1], nullptr, y, N);
    k_reduce<<<rb, 256, 0, stream>>>(rowptr, col, wval, y, red, N);
    k_ffn<256, true><<<gb, 256, 0, stream>>>(xA, red, Wh[2], Wl[2], Bp[2], xA, y, N);   // x1 -> y
    // conv2
    k_ffn<128, false><<<gb, 256, 0, stream>>>(y, nullptr, Wh[3], Wl[3], Bp[3], nullptr, xA, N);
    k_reduce<<<rb, 256, 0, stream>>>(rowptr, col, wval, xA, red, N);
    k_ffn<256, true><<<gb, 256, 0, stream>>>(y, red, Wh[4], Wl[4], Bp[4], y, xA, N);    // x2 -> xA
    // post + logits
    k_ffn<128, false><<<gb, 256, 0, stream>>>(xA, nullptr, Wh[5], Wl[5], Bp[5], nullptr, y, N);
    k_logits<<<(B + 3) / 4, 256, 0, stream>>>(y, input_idx, logits_w, logits_b, (float*)d_out, B);
}

// Round 5
// 483.279 us; speedup vs baseline: 6.6625x; 1.1154x over previous
//
#include <hip/hip_runtime.h>
#include <hip/hip_fp16.h>
#include <math.h>

static constexpr int D = 128;
static constexpr float EPS_BN = 1e-3f;

typedef short short8 __attribute__((ext_vector_type(8)));
typedef short short4v __attribute__((ext_vector_type(4)));
typedef float float4v __attribute__((ext_vector_type(4)));

__device__ __forceinline__ float gelu_exact(float x) {
    return 0.5f * x * (1.0f + erff(x * 0.70710678118654752f));
}

// split fp32 into bf16 hi (truncate) + bf16 lo (truncate of remainder): x ~ hi + lo
__device__ __forceinline__ void f32_to_hilo(float f, short& h, short& l) {
    unsigned u = __float_as_uint(f);
    h = (short)(u >> 16);
    float hf = __uint_as_float(u & 0xFFFF0000u);
    unsigned lu = __float_as_uint(f - hf);
    l = (short)(lu >> 16);
}

// ---------------- edge-weight sum ----------------
__global__ void k_sum(const float* __restrict__ w, int n, float* __restrict__ out) {
    float s = 0.f;
    for (int i = blockIdx.x * blockDim.x + threadIdx.x; i < n; i += gridDim.x * blockDim.x)
        s += w[i];
    for (int off = 32; off > 0; off >>= 1) s += __shfl_down(s, off, 64);
    __shared__ float sm[4];
    int lane = threadIdx.x & 63, wv = threadIdx.x >> 6;
    if (lane == 0) sm[wv] = s;
    __syncthreads();
    if (threadIdx.x == 0) atomicAdd(out, sm[0] + sm[1] + sm[2] + sm[3]);
}

__global__ void k_recip(float* s) { s[1] = 1.0f / s[0]; }

// ---------------- fold BN into weights, pre-split to bf16 hi/lo ----------------
struct FoldArgs {
    const float* g[6]; const float* be[6]; const float* mu[6];
    const float* var[6]; const float* w[6]; const float* bi[6];
    short* wh[6]; short* wl[6]; float* bp[6]; int K[6];
};

__global__ void k_fold_all(FoldArgs fa) {
    const int f = blockIdx.y;
    const int c = blockIdx.x; // 0..127
    const int K = fa.K[f];
    const float* g = fa.g[f]; const float* be = fa.be[f];
    const float* mu = fa.mu[f]; const float* var = fa.var[f];
    const float* w = fa.w[f]; const float* bi = fa.bi[f];
    short* wh = fa.wh[f]; short* wl = fa.wl[f]; float* bp = fa.bp[f];
    float part = 0.f;
    for (int k = threadIdx.x; k < K; k += blockDim.x) {
        float a = g[k] / sqrtf(var[k] + EPS_BN);
        float wv = w[k * D + c];
        float prod = a * wv;
        short hh, ll;
        f32_to_hilo(prod, hh, ll);
        wh[c * K + k] = hh;
        wl[c * K + k] = ll;
        part += (be[k] - mu[k] * a) * wv;
    }
    for (int off = 32; off > 0; off >>= 1) part += __shfl_down(part, off, 64);
    __shared__ float sm[4];
    int lane = threadIdx.x & 63, wv_ = threadIdx.x >> 6;
    if (lane == 0) sm[wv_] = part;
    __syncthreads();
    if (threadIdx.x == 0) bp[c] = bi[c] + sm[0] + sm[1] + sm[2] + sm[3];
}

// ---------------- CSR build ----------------
__global__ void k_hist(const int* __restrict__ edges, int* __restrict__ cnt, int E) {
    int e = blockIdx.x * blockDim.x + threadIdx.x;
    if (e < E) atomicAdd(&cnt[edges[e]], 1);
}

__global__ void k_scan1(const int* __restrict__ cnt, int* __restrict__ rowptr,
                        int* __restrict__ bsum, int N) {
    __shared__ int sm[1024];
    int t = threadIdx.x;
    int i = blockIdx.x * 1024 + t;
    int c = (i < N) ? cnt[i] : 0;
    sm[t] = c;
    __syncthreads();
    #pragma unroll
    for (int off = 1; off < 1024; off <<= 1) {
        int v = (t >= off) ? sm[t - off] : 0;
        __syncthreads();
        sm[t] += v;
        __syncthreads();
    }
    if (i < N) rowptr[i] = sm[t] - c;
    if (t == 1023) bsum[blockIdx.x] = sm[1023];
}

__global__ void k_scan2(int* __restrict__ bsum, int* __restrict__ bpre,
                        int* __restrict__ rowptr, int nb, int N) {
    int lane = threadIdx.x;
    int v = (lane < nb) ? bsum[lane] : 0;
    #pragma unroll
    for (int off = 1; off < 64; off <<= 1) {
        int u = __shfl_up(v, off, 64);
        if (lane >= off) v += u;
    }
    if (lane < nb) bpre[lane] = v;
    if (lane == nb - 1) rowptr[N] = v;
}

__global__ void k_scan3(int* __restrict__ rowptr, int* __restrict__ pos,
                        const int* __restrict__ bpre, int N) {
    int i = blockIdx.x * 1024 + threadIdx.x;
    if (i >= N) return;
    int off = (blockIdx.x > 0) ? bpre[blockIdx.x - 1] : 0;
    int r = rowptr[i] + off;
    rowptr[i] = r;
    pos[i] = r;
}

__global__ void k_fill(const int* __restrict__ edges, const float* __restrict__ ew,
                       const float* __restrict__ sums, int* __restrict__ pos,
                       int* __restrict__ col, float* __restrict__ wval, int E) {
    int e = blockIdx.x * blockDim.x + threadIdx.x;
    if (e >= E) return;
    int dst = edges[e], src = edges[E + e];
    int idx = atomicAdd(&pos[dst], 1);
    col[idx] = src;
    wval[idx] = ew[e] * sums[1];
}

// ---------------- CSR gather-reduce (fp16 payload): red[n] = sum_e w[e]*y[col[e]]
// quarter-wave per edge: 16 lanes x 16B = one 256B coalesced row; 4 edges in flight.
__global__ void k_reduce(const int* __restrict__ rowptr, const int* __restrict__ col,
                         const float* __restrict__ wval, const __half* __restrict__ y,
                         float* __restrict__ red, int N) {
    int n = blockIdx.x * (blockDim.x >> 6) + (threadIdx.x >> 6);
    if (n >= N) return;
    int lane = threadIdx.x & 63;
    int sub = lane >> 4;      // edge slot 0..3
    int q = lane & 15;        // 8-half chunk
    int start = rowptr[n], end = rowptr[n + 1];
    float acc[8] = {0.f, 0.f, 0.f, 0.f, 0.f, 0.f, 0.f, 0.f};
    int i = start + sub;
    if (i < end) {
        int src = col[i];
        float w = wval[i];
        for (;;) {
            int ni = i + 4;
            int nsrc = 0; float nw = 0.f;
            if (ni < end) { nsrc = col[ni]; nw = wval[ni]; }
            float4 raw = *((const float4*)(y + (size_t)src * D) + q);  // 8 halves, 16B
            const __half2* hp = (const __half2*)&raw;
            #pragma unroll
            for (int t = 0; t < 4; t++) {
                float2 f = __half22float2(hp[t]);
                acc[t * 2]     += w * f.x;
                acc[t * 2 + 1] += w * f.y;
            }
            if (ni >= end) break;
            i = ni; src = nsrc; w = nw;
        }
    }
    #pragma unroll
    for (int t = 0; t < 8; t++) {
        acc[t] += __shfl_xor(acc[t], 16, 64);
        acc[t] += __shfl_xor(acc[t], 32, 64);
    }
    if (sub == 0) {
        float4 o0 = {acc[0], acc[1], acc[2], acc[3]};
        float4 o1 = {acc[4], acc[5], acc[6], acc[7]};
        *((float4*)(red + (size_t)n * D + q * 8)) = o0;
        *((float4*)(red + (size_t)n * D + q * 8 + 4)) = o1;
    }
}

// ---------------- split-bf16 MFMA FFN: out = gelu(A @ W' + b'), optional l2norm+residual
// Block tile 128x128, 4 waves 2x2, each wave 4x4 grid of 16x16x32 MFMA tiles.
// X@W ~= Xh@Wh + Xh@Wl + Xl@Wh  (fp32 accumulate). OUT16: write __half output.
template<int K, bool L2RES, bool OUT16>
__global__ __launch_bounds__(256, 2) void k_ffn(
    const float* __restrict__ A0, const float* __restrict__ A1,
    const short* __restrict__ Wh, const short* __restrict__ Wl,
    const float* __restrict__ bp, const float* __restrict__ resid,
    float* __restrict__ outf, __half* __restrict__ outh, int nrows)
{
    __shared__ short Abuf[2][128][72];
    __shared__ short Wbuf[2][128][72];
    __shared__ float rs[128][2];

    const int tid = threadIdx.x;
    const int lane = tid & 63;
    const int wv = tid >> 6;
    const int wr = wv >> 1;
    const int wc = wv & 1;
    const int m = lane & 15;
    const int quad = lane >> 4;
    const int rowBlock = blockIdx.x * 128;

    float4v acc[4][4];
    #pragma unroll
    for (int ti = 0; ti < 4; ti++)
        #pragma unroll
        for (int tj = 0; tj < 4; tj++)
            acc[ti][tj] = (float4v){0.f, 0.f, 0.f, 0.f};

    for (int cc = 0; cc < K / 64; cc++) {
        const float* Asrc = (K == 256 && cc >= 2) ? A1 : A0;
        const int kb = (K == 256) ? ((cc & 1) * 64) : (cc * 64);
        const int kw = cc * 64;

        #pragma unroll
        for (int t = 0; t < 8; t++) {
            int i = tid + t * 256;
            int r = i >> 4, k4 = i & 15;
            int grow = rowBlock + r; if (grow >= nrows) grow = nrows - 1;
            float4 f = *((const float4*)(Asrc + (size_t)grow * D + kb) + k4);
            short h0, l0, h1, l1, h2, l2, h3, l3;
            f32_to_hilo(f.x, h0, l0);
            f32_to_hilo(f.y, h1, l1);
            f32_to_hilo(f.z, h2, l2);
            f32_to_hilo(f.w, h3, l3);
            short4v hh = {h0, h1, h2, h3};
            short4v ll = {l0, l1, l2, l3};
            *(short4v*)&Abuf[0][r][k4 * 4] = hh;
            *(short4v*)&Abuf[1][r][k4 * 4] = ll;
        }
        #pragma unroll
        for (int t = 0; t < 4; t++) {
            int i = tid + t * 256;
            int c = i >> 3, g = i & 7;
            short8 wh8 = *(const short8*)(Wh + (size_t)c * K + kw + g * 8);
            short8 wl8 = *(const short8*)(Wl + (size_t)c * K + kw + g * 8);
            *(short8*)&Wbuf[0][c][g * 8] = wh8;
            *(short8*)&Wbuf[1][c][g * 8] = wl8;
        }
        __syncthreads();

        #pragma unroll
        for (int ks = 0; ks < 2; ks++) {
            short8 ah[4], al[4], bh[4], bl[4];
            #pragma unroll
            for (int ti = 0; ti < 4; ti++) {
                ah[ti] = *(const short8*)&Abuf[0][wr * 64 + ti * 16 + m][ks * 32 + quad * 8];
                al[ti] = *(const short8*)&Abuf[1][wr * 64 + ti * 16 + m][ks * 32 + quad * 8];
            }
            #pragma unroll
            for (int tj = 0; tj < 4; tj++) {
                bh[tj] = *(const short8*)&Wbuf[0][wc * 64 + tj * 16 + m][ks * 32 + quad * 8];
                bl[tj] = *(const short8*)&Wbuf[1][wc * 64 + tj * 16 + m][ks * 32 + quad * 8];
            }
            #pragma unroll
            for (int ti = 0; ti < 4; ti++)
                #pragma unroll
                for (int tj = 0; tj < 4; tj++) {
                    acc[ti][tj] = __builtin_amdgcn_mfma_f32_16x16x32_bf16(al[ti], bh[tj], acc[ti][tj], 0, 0, 0);
                    acc[ti][tj] = __builtin_amdgcn_mfma_f32_16x16x32_bf16(ah[ti], bl[tj], acc[ti][tj], 0, 0, 0);
                    acc[ti][tj] = __builtin_amdgcn_mfma_f32_16x16x32_bf16(ah[ti], bh[tj], acc[ti][tj], 0, 0, 0);
                }
        }
        __syncthreads();
    }

    float bvv[4];
    #pragma unroll
    for (int tj = 0; tj < 4; tj++) bvv[tj] = bp[wc * 64 + tj * 16 + m];

    float g[4][4][4];
    #pragma unroll
    for (int ti = 0; ti < 4; ti++)
        #pragma unroll
        for (int tj = 0; tj < 4; tj++)
            #pragma unroll
            for (int r4 = 0; r4 < 4; r4++)
                g[ti][tj][r4] = gelu_exact(acc[ti][tj][r4] + bvv[tj]);

    if (L2RES) {
        #pragma unroll
        for (int ti = 0; ti < 4; ti++)
            #pragma unroll
            for (int r4 = 0; r4 < 4; r4++) {
                float ss = 0.f;
                #pragma unroll
                for (int tj = 0; tj < 4; tj++) ss += g[ti][tj][r4] * g[ti][tj][r4];
                ss += __shfl_xor(ss, 1, 64);
                ss += __shfl_xor(ss, 2, 64);
                ss += __shfl_xor(ss, 4, 64);
                ss += __shfl_xor(ss, 8, 64);
                if (m == 0) rs[wr * 64 + ti * 16 + quad * 4 + r4][wc] = ss;
            }
        __syncthreads();
        #pragma unroll
        for (int ti = 0; ti < 4; ti++)
            #pragma unroll
            for (int r4 = 0; r4 < 4; r4++) {
                int rib = wr * 64 + ti * 16 + quad * 4 + r4;
                float tot = rs[rib][0] + rs[rib][1];
                float inv = 1.0f / fmaxf(sqrtf(tot), 1e-12f);
                int row = rowBlock + rib;
                if (row < nrows) {
                    #pragma unroll
                    for (int tj = 0; tj < 4; tj++) {
                        int c = wc * 64 + tj * 16 + m;
                        outf[(size_t)row * D + c] = g[ti][tj][r4] * inv + resid[(size_t)row * D + c];
                    }
                }
            }
    } else {
        #pragma unroll
        for (int ti = 0; ti < 4; ti++)
            #pragma unroll
            for (int r4 = 0; r4 < 4; r4++) {
                int row = rowBlock + wr * 64 + ti * 16 + quad * 4 + r4;
                if (row < nrows) {
                    #pragma unroll
                    for (int tj = 0; tj < 4; tj++) {
                        int c = wc * 64 + tj * 16 + m;
                        if (OUT16) outh[(size_t)row * D + c] = __float2half(g[ti][tj][r4]);
                        else       outf[(size_t)row * D + c] = g[ti][tj][r4];
                    }
                }
            }
    }
}

// ---------------- gather + logits ----------------
__global__ void k_logits(const float* __restrict__ x, const int* __restrict__ idx,
                         const float* __restrict__ LW, const float* __restrict__ lb,
                         float* __restrict__ out, int B) {
    int wid = blockIdx.x * 4 + (threadIdx.x >> 6);
    int lane = threadIdx.x & 63;
    if (wid >= B) return;
    int row = __builtin_amdgcn_readfirstlane(idx[wid]);
    if (lane >= 40) return;
    float acc = lb[lane];
    const float4* xr = (const float4*)(x + (size_t)row * D);
    #pragma unroll 4
    for (int k4 = 0; k4 < 32; k4++) {
        float4 xv = xr[k4];
        acc += xv.x * LW[(4 * k4 + 0) * 40 + lane];
        acc += xv.y * LW[(4 * k4 + 1) * 40 + lane];
        acc += xv.z * LW[(4 * k4 + 2) * 40 + lane];
        acc += xv.w * LW[(4 * k4 + 3) * 40 + lane];
    }
    out[(size_t)wid * 40 + lane] = acc;
}

extern "C" void kernel_launch(void* const* d_in, const int* in_sizes, int n_in,
                              void* d_out, int out_size, void* d_ws, size_t ws_size,
                              hipStream_t stream) {
    const float* node_features = (const float*)d_in[0];
    const int*   edges         = (const int*)d_in[1];
    const float* edge_w        = (const float*)d_in[2];
    const int*   input_idx     = (const int*)d_in[3];
    const int N = in_sizes[0] / D;
    const int E = in_sizes[2];
    const int B = in_sizes[3];

    const float* P[6][6];
    for (int f = 0; f < 6; f++)
        for (int q = 0; q < 6; q++)
            P[f][q] = (const float*)d_in[4 + f * 6 + q];
    const float* logits_w = (const float*)d_in[40];
    const float* logits_b = (const float*)d_in[41];

    float* ws = (float*)d_ws;
    size_t nd = (size_t)N * D;
    float* xA  = ws;
    float* y   = ws + nd;
    float* red = ws + 2 * nd;
    float* p   = ws + 3 * nd;
    __half* yh = (__half*)p; p += nd / 2;       // fp16 message buffer
    const int Ks[6] = {128, 128, 256, 128, 256, 128};
    short* Wh[6]; short* Wl[6]; float* Bp[6];
    {
        short* sp = (short*)p;
        for (int f = 0; f < 6; f++) {
            Wh[f] = sp; sp += (size_t)Ks[f] * D;
            Wl[f] = sp; sp += (size_t)Ks[f] * D;
        }
        p = (float*)sp;
    }
    for (int f = 0; f < 6; f++) { Bp[f] = p; p += D; }
    float* sums = p; p += 2;
    int* rowptr = (int*)p; p += (N + 1);
    int* pos    = (int*)p; p += N;
    int* cnt    = (int*)p; p += N;
    int* bsum   = (int*)p; p += 64;
    int* bpre   = (int*)p; p += 64;
    int* col    = (int*)p; p += E;
    float* wval = p;       p += E;

    // edge-weight norm
    hipMemsetAsync(sums, 0, 2 * sizeof(float), stream);
    k_sum<<<512, 256, 0, stream>>>(edge_w, E, sums);
    k_recip<<<1, 1, 0, stream>>>(sums);

    // fold BN into weights, split to bf16 hi/lo
    FoldArgs fa;
    for (int f = 0; f < 6; f++) {
        fa.g[f] = P[f][0]; fa.be[f] = P[f][1]; fa.mu[f] = P[f][2];
        fa.var[f] = P[f][3]; fa.w[f] = P[f][4]; fa.bi[f] = P[f][5];
        fa.wh[f] = Wh[f]; fa.wl[f] = Wl[f]; fa.bp[f] = Bp[f]; fa.K[f] = Ks[f];
    }
    k_fold_all<<<dim3(D, 6), 256, 0, stream>>>(fa);

    // CSR build (shared by both convs)
    const int nb = (N + 1023) / 1024;
    hipMemsetAsync(cnt, 0, (size_t)N * sizeof(int), stream);
    k_hist<<<(E + 255) / 256, 256, 0, stream>>>(edges, cnt, E);
    k_scan1<<<nb, 1024, 0, stream>>>(cnt, rowptr, bsum, N);
    k_scan2<<<1, 64, 0, stream>>>(bsum, bpre, rowptr, nb, N);
    k_scan3<<<nb, 1024, 0, stream>>>(rowptr, pos, bpre, N);
    k_fill<<<(E + 255) / 256, 256, 0, stream>>>(edges, edge_w, sums, pos, col, wval, E);

    const int gb = (N + 127) / 128;
    const int rb = (N + 3) / 4;

    // pre
    k_ffn<128, false, false><<<gb, 256, 0, stream>>>(node_features, nullptr, Wh[0], Wl[0], Bp[0], nullptr, xA, nullptr, N);
    // conv1: prepare (fp16 out), CSR reduce, update+l2norm+residual
    k_ffn<128, false, true><<<gb, 256, 0, stream>>>(xA, nullptr, Wh[1], Wl[1], Bp[1], nullptr, nullptr, yh, N);
    k_reduce<<<rb, 256, 0, stream>>>(rowptr, col, wval, yh, red, N);
    k_ffn<256, true, false><<<gb, 256, 0, stream>>>(xA, red, Wh[2], Wl[2], Bp[2], xA, y, nullptr, N);   // x1 -> y
    // conv2
    k_ffn<128, false, true><<<gb, 256, 0, stream>>>(y, nullptr, Wh[3], Wl[3], Bp[3], nullptr, nullptr, yh, N);
    k_reduce<<<rb, 256, 0, stream>>>(rowptr, col, wval, yh, red, N);
    k_ffn<256, true, false><<<gb, 256, 0, stream>>>(y, red, Wh[4], Wl[4], Bp[4], y, xA, nullptr, N);    // x2 -> xA
    // post + logits
    k_ffn<128, false, false><<<gb, 256, 0, stream>>>(xA, nullptr, Wh[5], Wl[5], Bp[5], nullptr, y, nullptr, N);
    k_logits<<<(B + 3) / 4, 256, 0, stream>>>(y, input_idx, logits_w, logits_b, (float*)d_out, B);
}